// Round 1
// 73.465 us; speedup vs baseline: 1.0197x; 1.0197x over previous
//
#include <hip/hip_runtime.h>

#define NROWS 8192
#define DDIM 64
#define HDIM 256
#define HPAD 264   // bf16 elements per h_lds row (pad 256 -> 264 to spread banks)

using bf16x8 = __attribute__((ext_vector_type(8))) short;
using f32x4  = __attribute__((ext_vector_type(4))) float;

__device__ __forceinline__ unsigned short f2bf(float x) {
    unsigned u = __float_as_uint(x);
    u += 0x7FFFu + ((u >> 16) & 1u);   // round-to-nearest-even
    return (unsigned short)(u >> 16);
}

__device__ __forceinline__ float fast_tanh(float x) {
    // tanh(x) = 1 - 2/(exp(2x)+1); exp overflow -> rcp(inf)=0 -> 1; underflow -> -1
    float e = __expf(2.0f * x);
    return 1.0f - 2.0f * __builtin_amdgcn_rcpf(e + 1.0f);
}

// Single fused kernel: 16 rows per block, 256 threads (4 waves).
// Each wave holds its W1/W2 MFMA B-fragments in registers, converted from the
// fp32 weights directly (L2-resident: W1+W2 = 128 KB shared by all 512 blocks).
// Cb = b1 + t*wt and Sv[m] = sum_k W1[k,m]*W2[m,k] are computed in-kernel
// (Sv via per-quad partials + shfl_xor quad reduction) — no prep kernel, no ws.
__global__ __launch_bounds__(256)
void ode_fused(const float* __restrict__ t,
               const float* __restrict__ y,
               const float* __restrict__ W1,   // [64][256] row-major
               const float* __restrict__ b1,
               const float* __restrict__ wt,
               const float* __restrict__ W2,   // [256][64] row-major
               const float* __restrict__ b2,
               float* __restrict__ out) {
    const int tid  = threadIdx.x;
    const int w    = tid >> 6;     // wave 0..3 -> H columns [w*64, w*64+64)
    const int lane = tid & 63;
    const int l16  = lane & 15;
    const int quad = lane >> 4;
    const int row0 = blockIdx.x * 16;

    __shared__ __align__(16) unsigned short h_lds[16 * HPAD];  // h in bf16, [row][m] padded
    __shared__ float dvp[64];                                  // per-wave div partials [w][row]

    // ---- issue y loads first (HBM latency, longest pole)
    const float* yrow = y + (size_t)(row0 + l16) * DDIM;
    float4 yf[4];
    #pragma unroll
    for (int ks = 0; ks < 2; ++ks) {
        yf[2 * ks]     = *(const float4*)(yrow + ks * 32 + quad * 8);
        yf[2 * ks + 1] = *(const float4*)(yrow + ks * 32 + quad * 8 + 4);
    }

    const float t0   = t[0];
    const int  mbase = w * 64;
    const int  n     = w * 16 + l16;       // phase-2 output column 0..63

    // ---- W2 B-frags for phase 2: b[j] = bf16(W2[k0+j][n])
    //      (wave-coalesced: 16 consecutive n per quad -> 64 B segments, L2-hot)
    bf16x8 bfr2[8];
    #pragma unroll
    for (int ks = 0; ks < 8; ++ks) {
        const int k0 = ks * 32 + quad * 8;
        bf16x8 b;
        #pragma unroll
        for (int j = 0; j < 8; ++j) b[j] = (short)f2bf(W2[(k0 + j) * DDIM + n]);
        bfr2[ks] = b;
    }

    // ---- W1 B-frags for phase 1 + Cb + Sv.
    //      Each lane's quad covers k in [quad*8,quad*8+8) and [32+quad*8, ...):
    //      16 of the 64 k's -> Sv partial, reduced across quads via shfl_xor.
    bf16x8 bfr1[4][2];
    float  cb[4], sv[4];
    #pragma unroll
    for (int ct = 0; ct < 4; ++ct) {
        const int m = mbase + ct * 16 + l16;
        float s = 0.f;
        #pragma unroll
        for (int ks = 0; ks < 2; ++ks) {
            const int k0 = ks * 32 + quad * 8;
            const float4 r0 = *(const float4*)(W2 + m * DDIM + k0);      // W2 row m, contiguous
            const float4 r1 = *(const float4*)(W2 + m * DDIM + k0 + 4);
            const float w2r[8] = {r0.x, r0.y, r0.z, r0.w, r1.x, r1.y, r1.z, r1.w};
            bf16x8 b;
            #pragma unroll
            for (int j = 0; j < 8; ++j) {
                const float w1v = W1[(k0 + j) * HDIM + m];               // fp32, used twice
                b[j] = (short)f2bf(w1v);
                s += w1v * w2r[j];
            }
            bfr1[ct][ks] = b;
        }
        s += __shfl_xor(s, 16);    // quads 0<->1, 2<->3
        s += __shfl_xor(s, 32);    // pairs <-> pairs: all 4 quads summed
        sv[ct] = s;
        cb[ct] = b1[m] + t0 * wt[m];
    }

    // ---- convert y to bf16 A-frags. A[m=l16(row)][k=quad*8+j]
    bf16x8 afr[2];
    #pragma unroll
    for (int ks = 0; ks < 2; ++ks) {
        const float4 f0 = yf[2 * ks], f1 = yf[2 * ks + 1];
        bf16x8 a;
        a[0] = (short)f2bf(f0.x); a[1] = (short)f2bf(f0.y);
        a[2] = (short)f2bf(f0.z); a[3] = (short)f2bf(f0.w);
        a[4] = (short)f2bf(f1.x); a[5] = (short)f2bf(f1.y);
        a[6] = (short)f2bf(f1.z); a[7] = (short)f2bf(f1.w);
        afr[ks] = a;
    }

    // ---- phase 1: z = y @ W1  (wave w covers 4 column tiles of 16)
    f32x4 acc[4];
    #pragma unroll
    for (int ct = 0; ct < 4; ++ct) acc[ct] = (f32x4){0.f, 0.f, 0.f, 0.f};

    #pragma unroll
    for (int ct = 0; ct < 4; ++ct) {
        #pragma unroll
        for (int ks = 0; ks < 2; ++ks)
            acc[ct] = __builtin_amdgcn_mfma_f32_16x16x32_bf16(afr[ks], bfr1[ct][ks], acc[ct], 0, 0, 0);
    }

    // ---- bias + tanh + divergence partials; store h (bf16) to LDS in [row][m]
    float dv[4] = {0.f, 0.f, 0.f, 0.f};
    #pragma unroll
    for (int ct = 0; ct < 4; ++ct) {
        const int m = mbase + ct * 16 + l16;
        #pragma unroll
        for (int r = 0; r < 4; ++r) {             // C layout: col=l16, row=quad*4+r
            float z = acc[ct][r] + cb[ct];
            float h = fast_tanh(z);
            dv[r] += (1.f - h * h) * sv[ct];
            h_lds[(quad * 4 + r) * HPAD + m] = f2bf(h);
        }
    }
    // reduce dv over the 16 lanes of this quad group (same rows, different cols)
    #pragma unroll
    for (int off = 8; off; off >>= 1) {
        #pragma unroll
        for (int r = 0; r < 4; ++r) dv[r] += __shfl_down(dv[r], off, 16);
    }
    if (l16 == 0) {
        #pragma unroll
        for (int r = 0; r < 4; ++r) dvp[w * 16 + quad * 4 + r] = dv[r];
    }
    __syncthreads();

    // ---- phase 2: dy = h @ W2 (wave w computes output cols [w*16, w*16+16))
    f32x4 acc2 = (f32x4){0.f, 0.f, 0.f, 0.f};
    #pragma unroll
    for (int ks = 0; ks < 8; ++ks) {
        bf16x8 a = *(const bf16x8*)(&h_lds[l16 * HPAD + ks * 32 + quad * 8]);
        acc2 = __builtin_amdgcn_mfma_f32_16x16x32_bf16(a, bfr2[ks], acc2, 0, 0, 0);
    }
    const float b2v = b2[n];
    #pragma unroll
    for (int r = 0; r < 4; ++r) {
        const int row = quad * 4 + r;
        out[(size_t)(row0 + row) * (DDIM + 1) + n] = acc2[r] + b2v;
    }

    // ---- divergence column (col 64): sum the 4 wave partials per row
    if (w == 0 && lane < 16) {
        float s = dvp[lane] + dvp[16 + lane] + dvp[32 + lane] + dvp[48 + lane];
        out[(size_t)(row0 + lane) * (DDIM + 1) + DDIM] = -s;
    }
}

extern "C" void kernel_launch(void* const* d_in, const int* in_sizes, int n_in,
                              void* d_out, int out_size, void* d_ws, size_t ws_size,
                              hipStream_t stream) {
    const float* t  = (const float*)d_in[0];
    const float* y  = (const float*)d_in[1];
    const float* W1 = (const float*)d_in[2];
    const float* b1 = (const float*)d_in[3];
    const float* wt = (const float*)d_in[4];
    const float* W2 = (const float*)d_in[5];
    const float* b2 = (const float*)d_in[6];
    float* out = (float*)d_out;

    (void)d_ws; (void)ws_size;  // no workspace: prep is fused

    ode_fused<<<NROWS / 16, 256, 0, stream>>>(t, y, W1, b1, wt, W2, b2, out);
}